// Round 1
// baseline (20303.375 us; speedup 1.0000x reference)
//
#include <hip/hip_runtime.h>
#include <math.h>

#define BB   256   // batch
#define HH   512   // hidden
#define NWG  256
#define NTHR 256
#define TT   64    // steps
#define NOUT 33
#define CD   128   // cond dim
#define SZ   (HH*BB)

__device__ __forceinline__ float sigm(float x)  { return 1.0f/(1.0f+expf(-x)); }
__device__ __forceinline__ float lrelu(float x) { return x >= 0.0f ? x : 0.01f*x; }

// Device-scope sense-reversing grid barrier. cnt at bar[0], gen at bar[16] (64B apart).
__device__ __forceinline__ void gbar(unsigned* bar) {
  __syncthreads();
  if (threadIdx.x == 0) {
    unsigned* cnt = bar;
    unsigned* gen = bar + 16;
    unsigned g = __hip_atomic_load(gen, __ATOMIC_RELAXED, __HIP_MEMORY_SCOPE_AGENT);
    unsigned prev = __hip_atomic_fetch_add(cnt, 1u, __ATOMIC_ACQ_REL, __HIP_MEMORY_SCOPE_AGENT);
    if (prev == NWG - 1u) {
      __hip_atomic_store(cnt, 0u, __ATOMIC_RELAXED, __HIP_MEMORY_SCOPE_AGENT);
      __hip_atomic_fetch_add(gen, 1u, __ATOMIC_RELEASE, __HIP_MEMORY_SCOPE_AGENT);
    } else {
      while (__hip_atomic_load(gen, __ATOMIC_RELAXED, __HIP_MEMORY_SCOPE_AGENT) == g) {
        __builtin_amdgcn_s_sleep(2);
      }
      __builtin_amdgcn_fence(__ATOMIC_ACQUIRE, "agent");
    }
  }
  __syncthreads();
}

// One LSTM cell phase: this WG owns hidden units hu0, hu0+1 (their 4 gates each)
// for all 256 batch rows. Weights via wave-uniform scalar loads; activations
// read transposed [H][B] so lane b is coalesced.
__device__ __forceinline__ void lstm_phase(
    const float* __restrict__ Wi, const float* __restrict__ Wh,
    const float* __restrict__ bi, const float* __restrict__ bh,
    const float* __restrict__ xsrc, const float* __restrict__ hsrc,
    float* __restrict__ hdst, float* __restrict__ cbuf,
    int hu0, int b)
{
  float acc[2][4];
  #pragma unroll
  for (int u = 0; u < 2; ++u)
    #pragma unroll
    for (int g = 0; g < 4; ++g)
      acc[u][g] = bi[g*HH + hu0 + u] + bh[g*HH + hu0 + u];

  #pragma unroll 4
  for (int k = 0; k < HH; ++k) {
    float xv = xsrc[k*BB + b];
    float hv = hsrc[k*BB + b];
    #pragma unroll
    for (int u = 0; u < 2; ++u) {
      #pragma unroll
      for (int g = 0; g < 4; ++g) {
        acc[u][g] += Wi[(g*HH + hu0 + u)*HH + k] * xv;
        acc[u][g] += Wh[(g*HH + hu0 + u)*HH + k] * hv;
      }
    }
  }
  // torch gate order i,f,g,o
  #pragma unroll
  for (int u = 0; u < 2; ++u) {
    int hu = hu0 + u;
    float ig = sigm(acc[u][0]);
    float fg = sigm(acc[u][1]);
    float gg = tanhf(acc[u][2]);
    float og = sigm(acc[u][3]);
    float cp = cbuf[hu*BB + b];
    float cn = fg*cp + ig*gg;
    float hn = og * tanhf(cn);
    cbuf[hu*BB + b] = cn;
    hdst[hu*BB + b] = hn;
  }
}

extern "C" __global__ void __launch_bounds__(NTHR)
decoder_kernel(const float* __restrict__ h0, const float* __restrict__ c0,
               const float* __restrict__ conds, const float* __restrict__ emb,
               const float* __restrict__ Wih, const float* __restrict__ Whh,
               const float* __restrict__ bih, const float* __restrict__ bhh,
               const float* __restrict__ fcW, const float* __restrict__ fcb,
               const float* __restrict__ fc2W, const float* __restrict__ fc2b,
               const float* __restrict__ fc3W, const float* __restrict__ fc3b,
               float* __restrict__ out, unsigned* bar, float* wsf)
{
  const int w   = blockIdx.x;   // WG id == owned hidden pair == owned batch row (fc3)
  const int tid = threadIdx.x;  // == batch row in GEMM phases

  // workspace: all activation buffers transposed [H][B]
  float* xbuf  = wsf;
  float* h1b0  = wsf + 1*SZ;
  float* h1b1  = wsf + 2*SZ;
  float* h2b0  = wsf + 3*SZ;
  float* h2b1  = wsf + 4*SZ;
  float* c1b   = wsf + 5*SZ;
  float* c2b   = wsf + 6*SZ;
  float* condb = wsf + 7*SZ;
  float* yb    = wsf + 8*SZ;

  __shared__ float lds_part[32][9];
  __shared__ float lds_part32[8];
  __shared__ float lds_y[HH];
  __shared__ int   lds_act;

  // ---- init: transpose-copy states, initial input (act=SOS=0, dur=0), cond branch ----
  {
    const int b = tid;
    #pragma unroll
    for (int kk = 0; kk < 2; ++kk) {
      const int k = 2*w + kk;
      xbuf[k*BB + b] = (k < HH-1) ? emb[k] : 0.0f;      // emb[0][k], dur=0
      h1b0[k*BB + b] = h0[b*HH + k];
      c1b [k*BB + b] = c0[b*HH + k];
      h2b0[k*BB + b] = h0[(BB + b)*HH + k];
      c2b [k*BB + b] = c0[(BB + b)*HH + k];
      float a = fcb[k];
      for (int q = 0; q < CD; ++q)
        a += conds[b*CD + q] * fcW[k*CD + q];
      condb[k*BB + b] = lrelu(a);
    }
  }
  gbar(bar);

  const int hu0 = 2*w;
  for (int t = 0; t < TT; ++t) {
    const bool par = (t & 1) != 0;
    float* h1r = par ? h1b1 : h1b0;
    float* h1w = par ? h1b0 : h1b1;
    float* h2r = par ? h2b1 : h2b0;
    float* h2w = par ? h2b0 : h2b1;

    // Phase A: layer 0
    lstm_phase(Wih, Whh, bih, bhh, xbuf, h1r, h1w, c1b, hu0, tid);
    gbar(bar);
    // Phase B: layer 1
    lstm_phase(Wih + 2048*512, Whh + 2048*512, bih + 2048, bhh + 2048,
               h1w, h2r, h2w, c2b, hu0, tid);
    gbar(bar);
    // Phase C: y = leaky((h2 + cond) @ fc2W.T + fc2b), rows hu0..hu0+1
    {
      const int b = tid;
      float a0 = fc2b[hu0], a1 = fc2b[hu0+1];
      #pragma unroll 4
      for (int k = 0; k < HH; ++k) {
        float hv = h2w[k*BB + b] + condb[k*BB + b];
        a0 += fc2W[hu0*HH + k]     * hv;
        a1 += fc2W[(hu0+1)*HH + k] * hv;
      }
      yb[hu0*BB + b]     = lrelu(a0);
      yb[(hu0+1)*BB + b] = lrelu(a1);
    }
    gbar(bar);
    // Phase D: WG w handles batch row w: pred = y@fc3W.T + fc3b, argmax, next x
    {
      for (int k = tid; k < HH; k += NTHR) lds_y[k] = yb[k*BB + w];
      __syncthreads();
      const int o  = tid & 31;
      const int kc = tid >> 5;   // 8 chunks of 64
      float p = 0.0f;
      for (int k2 = 0; k2 < 64; ++k2) {
        int k = kc*64 + k2;
        p += fc3W[o*HH + k] * lds_y[k];
      }
      lds_part[o][kc] = p;
      if (tid < 8) {
        float p2 = 0.0f;
        for (int k2 = 0; k2 < 64; ++k2) {
          int k = tid*64 + k2;
          p2 += fc3W[32*HH + k] * lds_y[k];
        }
        lds_part32[tid] = p2;
      }
      __syncthreads();
      float predv = -1e30f;
      if (tid < NOUT) {
        float s = fc3b[tid];
        #pragma unroll
        for (int kc2 = 0; kc2 < 8; ++kc2)
          s += (tid < 32) ? lds_part[tid][kc2] : lds_part32[kc2];
        predv = s;
        out[(w*TT + t)*NOUT + tid] = s;   // raw logits; post-processed at the end
      }
      if (tid < 64) {  // wave 0: argmax over 32 activity logits (first-max tie-break)
        float v  = (tid < 32) ? predv : -1e30f;
        int   idx = tid;
        #pragma unroll
        for (int off = 32; off > 0; off >>= 1) {
          float ov = __shfl_xor(v, off);
          int   oi = __shfl_xor(idx, off);
          if (ov > v || (ov == v && oi < idx)) { v = ov; idx = oi; }
        }
        if (tid == 0) lds_act = idx;
      }
      __syncthreads();
      const int act = lds_act;
      for (int k = tid; k < HH; k += NTHR)
        xbuf[k*BB + w] = (k < HH-1) ? emb[act*(HH-1) + k] : 1.0f;  // dur=1
    }
    gbar(bar);
  }

  // ---- postprocess row w: log_softmax over 32 logits; softmax over time for dur ----
  if (tid < TT) {
    const int s = tid;  // wave 0 exactly
    float* po = out + (w*TT + s)*NOUT;
    float v[NOUT];
    #pragma unroll
    for (int o = 0; o < NOUT; ++o) v[o] = po[o];
    float m = v[0];
    #pragma unroll
    for (int o = 1; o < 32; ++o) m = fmaxf(m, v[o]);
    float sum = 0.0f;
    #pragma unroll
    for (int o = 0; o < 32; ++o) sum += expf(v[o] - m);
    float lse = m + logf(sum);
    #pragma unroll
    for (int o = 0; o < 32; ++o) po[o] = v[o] - lse;
    float d = v[32];
    float dm = d;
    #pragma unroll
    for (int off = 32; off > 0; off >>= 1) dm = fmaxf(dm, __shfl_xor(dm, off));
    float e = expf(d - dm);
    float es = e;
    #pragma unroll
    for (int off = 32; off > 0; off >>= 1) es += __shfl_xor(es, off);
    po[32] = e / es;
  }
}

extern "C" void kernel_launch(void* const* d_in, const int* in_sizes, int n_in,
                              void* d_out, int out_size, void* d_ws, size_t ws_size,
                              hipStream_t stream) {
  // setup_inputs order: batch_size, h0, c0, conditionals, emb, Wih, Whh, bih, bhh,
  //                     fcW, fcb, fc2W, fc2b, fc3W, fc3b
  const float* h0   = (const float*)d_in[1];
  const float* c0   = (const float*)d_in[2];
  const float* cnd  = (const float*)d_in[3];
  const float* emb  = (const float*)d_in[4];
  const float* Wih  = (const float*)d_in[5];
  const float* Whh  = (const float*)d_in[6];
  const float* bih  = (const float*)d_in[7];
  const float* bhh  = (const float*)d_in[8];
  const float* fcW  = (const float*)d_in[9];
  const float* fcb  = (const float*)d_in[10];
  const float* fc2W = (const float*)d_in[11];
  const float* fc2b = (const float*)d_in[12];
  const float* fc3W = (const float*)d_in[13];
  const float* fc3b = (const float*)d_in[14];

  unsigned* bar = (unsigned*)d_ws;
  float* wsf = (float*)((char*)d_ws + 256);

  // reset barrier state every call (d_ws is poisoned once, never re-poisoned)
  (void)hipMemsetAsync(d_ws, 0, 256, stream);

  hipLaunchKernelGGL(decoder_kernel, dim3(NWG), dim3(NTHR), 0, stream,
                     h0, c0, cnd, emb, Wih, Whh, bih, bhh, fcW, fcb,
                     fc2W, fc2b, fc3W, fc3b, (float*)d_out, bar, wsf);
}

// Round 2
// 13571.107 us; speedup vs baseline: 1.4961x; 1.4961x over previous
//
#include <hip/hip_runtime.h>
#include <math.h>

#define BB   256   // batch
#define HH   512   // hidden
#define NWG  256
#define NTHR 256
#define TT   64    // steps
#define NOUT 33
#define CD   128   // cond dim
#define SZ   (HH*BB)
#define LOFF (4*HH*HH)   // layer stride in Wih/Whh
#define BOFF (4*HH)      // layer stride in bih/bhh

__device__ __forceinline__ float sigm(float x)  { return 1.0f/(1.0f+expf(-x)); }
__device__ __forceinline__ float lrelu(float x) { return x >= 0.0f ? x : 0.01f*x; }

// Monotonic 2-level grid barrier: 8 group counters (32 arrivals each) -> 1 global
// counter (8 arrivals) -> gen broadcast. No resets, no reset races.
__device__ __forceinline__ void gbar(unsigned* bar, unsigned ep, int grp) {
  __syncthreads();
  if (threadIdx.x == 0) {
    __builtin_amdgcn_fence(__ATOMIC_RELEASE, "agent");
    unsigned old = __hip_atomic_fetch_add(&bar[grp*16], 1u, __ATOMIC_ACQ_REL, __HIP_MEMORY_SCOPE_AGENT);
    if (old == ep*32u + 31u) {
      unsigned o2 = __hip_atomic_fetch_add(&bar[128], 1u, __ATOMIC_ACQ_REL, __HIP_MEMORY_SCOPE_AGENT);
      if (o2 == ep*8u + 7u)
        __hip_atomic_store(&bar[144], ep+1u, __ATOMIC_RELEASE, __HIP_MEMORY_SCOPE_AGENT);
    }
    while (__hip_atomic_load(&bar[144], __ATOMIC_ACQUIRE, __HIP_MEMORY_SCOPE_AGENT) < ep+1u)
      __builtin_amdgcn_s_sleep(2);
    __builtin_amdgcn_fence(__ATOMIC_ACQUIRE, "agent");
  }
  __syncthreads();
}

__device__ __forceinline__ void ld8(const float* __restrict__ src, int kbase, int b, float* dst) {
  #pragma unroll
  for (int j = 0; j < 8; ++j) dst[j] = src[(kbase+j)*BB + b];
}

// 8 k-steps of the LSTM gate GEMM: weights from LDS [k][16] (broadcast b128 reads)
__device__ __forceinline__ void fma8(const float* wl, int kbase,
                                     const float* xv, const float* hv, float* acc) {
  #pragma unroll
  for (int j = 0; j < 8; ++j) {
    const float* wr = wl + (kbase+j)*16;
    float4 wi0 = *(const float4*)(wr);
    float4 wi1 = *(const float4*)(wr+4);
    float4 wh0 = *(const float4*)(wr+8);
    float4 wh1 = *(const float4*)(wr+12);
    float x = xv[j], h = hv[j];
    acc[0] += wi0.x*x + wh0.x*h;
    acc[1] += wi0.y*x + wh0.y*h;
    acc[2] += wi0.z*x + wh0.z*h;
    acc[3] += wi0.w*x + wh0.w*h;
    acc[4] += wi1.x*x + wh1.x*h;
    acc[5] += wi1.y*x + wh1.y*h;
    acc[6] += wi1.z*x + wh1.z*h;
    acc[7] += wi1.w*x + wh1.w*h;
  }
}

// One LSTM cell phase: WG owns hidden units hu0,hu0+1 (8 gate rows) for all 256 b.
// Weights in LDS; activations from global with 2-deep register prefetch.
__device__ __forceinline__ void lstm_phase(const float* wl, const float* bias,
    const float* __restrict__ xsrc, const float* __restrict__ hsrc,
    float* __restrict__ hdst, float* __restrict__ cbuf, int hu0, int b)
{
  float acc[8];
  #pragma unroll
  for (int r = 0; r < 8; ++r) acc[r] = bias[r];

  float xa[8], ha[8], xb[8], hb[8];
  ld8(xsrc, 0, b, xa); ld8(hsrc, 0, b, ha);
  ld8(xsrc, 8, b, xb); ld8(hsrc, 8, b, hb);

  #pragma unroll 1
  for (int blk = 0; blk < 64; blk += 2) {
    fma8(wl, blk*8, xa, ha, acc);
    if (blk+2 < 64) { ld8(xsrc, (blk+2)*8, b, xa); ld8(hsrc, (blk+2)*8, b, ha); }
    fma8(wl, (blk+1)*8, xb, hb, acc);
    if (blk+3 < 64) { ld8(xsrc, (blk+3)*8, b, xb); ld8(hsrc, (blk+3)*8, b, hb); }
  }
  // torch gate order i,f,g,o ; slot = u*4+g
  #pragma unroll
  for (int u = 0; u < 2; ++u) {
    int hu = hu0 + u;
    float ig = sigm(acc[u*4+0]);
    float fg = sigm(acc[u*4+1]);
    float gg = tanhf(acc[u*4+2]);
    float og = sigm(acc[u*4+3]);
    float cp = cbuf[hu*BB + b];
    float cn = fg*cp + ig*gg;
    float hn = og * tanhf(cn);
    cbuf[hu*BB + b] = cn;
    hdst[hu*BB + b] = hn;
  }
}

extern "C" __global__ void __launch_bounds__(NTHR)
decoder_kernel(const float* __restrict__ h0, const float* __restrict__ c0,
               const float* __restrict__ conds, const float* __restrict__ emb,
               const float* __restrict__ Wih, const float* __restrict__ Whh,
               const float* __restrict__ bih, const float* __restrict__ bhh,
               const float* __restrict__ fcW, const float* __restrict__ fcb,
               const float* __restrict__ fc2W, const float* __restrict__ fc2b,
               const float* __restrict__ fc3W, const float* __restrict__ fc3b,
               float* __restrict__ out, unsigned* bar, float* wsf)
{
  const int w   = blockIdx.x;
  const int tid = threadIdx.x;
  const int hu0 = 2*w;
  const int grp = w & 7;

  float* xbuf  = wsf;
  float* h1b0  = wsf + 1*SZ;
  float* h1b1  = wsf + 2*SZ;
  float* h2b0  = wsf + 3*SZ;
  float* h2b1  = wsf + 4*SZ;
  float* c1b   = wsf + 5*SZ;
  float* c2b   = wsf + 6*SZ;
  float* condb = wsf + 7*SZ;
  float* yb    = wsf + 8*SZ;

  __shared__ float wl1[HH*16];    // 32KB  [k][ Wi(u*4+g)=0..7 | Wh=8..15 ]
  __shared__ float wl2[HH*16];    // 32KB
  __shared__ float wfc2[HH*2];    // 4KB   [k][u]
  __shared__ float bias1[8], bias2[8], biasc[2];
  __shared__ float lds_y[HH];
  __shared__ float lds_part[32][9];
  __shared__ float lds_part32[8];
  __shared__ int   lds_act;
  __shared__ float lds_pad[2200]; // push LDS > 80KB -> exactly 1 WG/CU
  if (tid == 0) ((volatile float*)lds_pad)[0] = 0.0f;

  // ---- init: transposed state copies, x0, cond branch, weight staging ----
  {
    const int b = tid;
    #pragma unroll
    for (int kk = 0; kk < 2; ++kk) {
      const int k = hu0 + kk;
      xbuf[k*BB + b] = (k < HH-1) ? emb[k] : 0.0f;   // emb[SOS=0][k], dur=0
      h1b0[k*BB + b] = h0[b*HH + k];
      c1b [k*BB + b] = c0[b*HH + k];
      h2b0[k*BB + b] = h0[(BB + b)*HH + k];
      c2b [k*BB + b] = c0[(BB + b)*HH + k];
      float a = fcb[k];
      for (int q = 0; q < CD; ++q)
        a += conds[b*CD + q] * fcW[k*CD + q];
      condb[k*BB + b] = lrelu(a);
    }
  }
  for (int i = tid; i < 8*HH; i += NTHR) {
    int k = i & (HH-1), ri = i >> 9;
    int u = ri >> 2, g = ri & 3;
    int row = g*HH + hu0 + u;
    wl1[k*16 + ri]     = Wih[row*HH + k];
    wl1[k*16 + 8 + ri] = Whh[row*HH + k];
    wl2[k*16 + ri]     = Wih[LOFF + row*HH + k];
    wl2[k*16 + 8 + ri] = Whh[LOFF + row*HH + k];
  }
  for (int i = tid; i < 2*HH; i += NTHR) {
    int k = i >> 1, u = i & 1;
    wfc2[k*2 + u] = fc2W[(hu0+u)*HH + k];
  }
  if (tid < 8) {
    int u = tid >> 2, g = tid & 3;
    bias1[tid] = bih[g*HH + hu0 + u] + bhh[g*HH + hu0 + u];
    bias2[tid] = bih[BOFF + g*HH + hu0 + u] + bhh[BOFF + g*HH + hu0 + u];
  }
  if (tid < 2) biasc[tid] = fc2b[hu0 + tid];

  unsigned ep = 0;
  gbar(bar, ep++, grp);

  // condY = cond @ fc2W^T rows hu0,hu0+1 (step-invariant, kept in registers)
  float cy0 = 0.0f, cy1 = 0.0f;
  {
    const int b = tid;
    #pragma unroll 8
    for (int k = 0; k < HH; ++k) {
      float cv = condb[k*BB + b];
      float2 wv = *(const float2*)(wfc2 + k*2);
      cy0 += wv.x*cv; cy1 += wv.y*cv;
    }
  }

  for (int t = 0; t < TT; ++t) {
    const bool par = (t & 1) != 0;
    float* h1r = par ? h1b1 : h1b0;
    float* h1w = par ? h1b0 : h1b1;
    float* h2r = par ? h2b1 : h2b0;
    float* h2w = par ? h2b0 : h2b1;

    // Phase A: layer 0
    lstm_phase(wl1, bias1, xbuf, h1r, h1w, c1b, hu0, tid);
    gbar(bar, ep++, grp);
    // Phase B: layer 1
    lstm_phase(wl2, bias2, h1w, h2r, h2w, c2b, hu0, tid);
    gbar(bar, ep++, grp);
    // Phase C: y = leaky(h2 @ fc2W^T + fc2b + condY)
    {
      const int b = tid;
      float a0 = biasc[0] + cy0, a1 = biasc[1] + cy1;
      float va[8], vb[8];
      ld8(h2w, 0, b, va);
      ld8(h2w, 8, b, vb);
      #pragma unroll 1
      for (int blk = 0; blk < 64; blk += 2) {
        #pragma unroll
        for (int j2 = 0; j2 < 4; ++j2) {   // 8 k via 4 x b128
          float4 wv = *(const float4*)(wfc2 + blk*16 + j2*4);
          a0 += wv.x*va[2*j2]   + wv.z*va[2*j2+1];
          a1 += wv.y*va[2*j2]   + wv.w*va[2*j2+1];
        }
        if (blk+2 < 64) ld8(h2w, (blk+2)*8, b, va);
        #pragma unroll
        for (int j2 = 0; j2 < 4; ++j2) {
          float4 wv = *(const float4*)(wfc2 + (blk+1)*16 + j2*4);
          a0 += wv.x*vb[2*j2]   + wv.z*vb[2*j2+1];
          a1 += wv.y*vb[2*j2]   + wv.w*vb[2*j2+1];
        }
        if (blk+3 < 64) ld8(h2w, (blk+3)*8, b, vb);
      }
      yb[hu0*BB + b]     = lrelu(a0);
      yb[(hu0+1)*BB + b] = lrelu(a1);
    }
    gbar(bar, ep++, grp);
    // Phase D: WG w handles batch row w: fc3, argmax, next x
    {
      for (int k = tid; k < HH; k += NTHR) lds_y[k] = yb[k*BB + w];
      __syncthreads();
      const int o  = tid & 31;
      const int kc = tid >> 5;
      float p = 0.0f;
      for (int k2 = 0; k2 < 64; ++k2) {
        int k = kc*64 + k2;
        p += fc3W[o*HH + k] * lds_y[k];
      }
      lds_part[o][kc] = p;
      if (tid < 8) {
        float p2 = 0.0f;
        for (int k2 = 0; k2 < 64; ++k2) {
          int k = tid*64 + k2;
          p2 += fc3W[32*HH + k] * lds_y[k];
        }
        lds_part32[tid] = p2;
      }
      __syncthreads();
      float predv = -1e30f;
      if (tid < NOUT) {
        float s = fc3b[tid];
        #pragma unroll
        for (int kc2 = 0; kc2 < 8; ++kc2)
          s += (tid < 32) ? lds_part[tid][kc2] : lds_part32[kc2];
        predv = s;
        out[(w*TT + t)*NOUT + tid] = s;
      }
      if (tid < 64) {
        float v  = (tid < 32) ? predv : -1e30f;
        int  idx = tid;
        #pragma unroll
        for (int off = 32; off > 0; off >>= 1) {
          float ov = __shfl_xor(v, off);
          int   oi = __shfl_xor(idx, off);
          if (ov > v || (ov == v && oi < idx)) { v = ov; idx = oi; }
        }
        if (tid == 0) lds_act = idx;
      }
      __syncthreads();
      const int act = lds_act;
      for (int k = tid; k < HH; k += NTHR)
        xbuf[k*BB + w] = (k < HH-1) ? emb[act*(HH-1) + k] : 1.0f;
    }
    gbar(bar, ep++, grp);
  }

  // ---- postprocess row w ----
  if (tid < TT) {
    const int s = tid;
    float* po = out + (w*TT + s)*NOUT;
    float v[NOUT];
    #pragma unroll
    for (int o = 0; o < NOUT; ++o) v[o] = po[o];
    float m = v[0];
    #pragma unroll
    for (int o = 1; o < 32; ++o) m = fmaxf(m, v[o]);
    float sum = 0.0f;
    #pragma unroll
    for (int o = 0; o < 32; ++o) sum += expf(v[o] - m);
    float lse = m + logf(sum);
    #pragma unroll
    for (int o = 0; o < 32; ++o) po[o] = v[o] - lse;
    float d = v[32];
    float dm = d;
    #pragma unroll
    for (int off = 32; off > 0; off >>= 1) dm = fmaxf(dm, __shfl_xor(dm, off));
    float e = expf(d - dm);
    float es = e;
    #pragma unroll
    for (int off = 32; off > 0; off >>= 1) es += __shfl_xor(es, off);
    po[32] = e / es;
  }
}

extern "C" void kernel_launch(void* const* d_in, const int* in_sizes, int n_in,
                              void* d_out, int out_size, void* d_ws, size_t ws_size,
                              hipStream_t stream) {
  const float* h0   = (const float*)d_in[1];
  const float* c0   = (const float*)d_in[2];
  const float* cnd  = (const float*)d_in[3];
  const float* emb  = (const float*)d_in[4];
  const float* Wih  = (const float*)d_in[5];
  const float* Whh  = (const float*)d_in[6];
  const float* bih  = (const float*)d_in[7];
  const float* bhh  = (const float*)d_in[8];
  const float* fcW  = (const float*)d_in[9];
  const float* fcb  = (const float*)d_in[10];
  const float* fc2W = (const float*)d_in[11];
  const float* fc2b = (const float*)d_in[12];
  const float* fc3W = (const float*)d_in[13];
  const float* fc3b = (const float*)d_in[14];

  unsigned* bar = (unsigned*)d_ws;
  float* wsf = (float*)((char*)d_ws + 1024);

  (void)hipMemsetAsync(d_ws, 0, 1024, stream);

  hipLaunchKernelGGL(decoder_kernel, dim3(NWG), dim3(NTHR), 0, stream,
                     h0, c0, cnd, emb, Wih, Whh, bih, bhh, fcW, fcb,
                     fc2W, fc2b, fc3W, fc3b, (float*)d_out, bar, wsf);
}